// Round 10
// baseline (316.948 us; speedup 1.0000x reference)
//
#include <hip/hip_runtime.h>

typedef unsigned short u16;
typedef __attribute__((ext_vector_type(8))) unsigned short u16x8;
typedef __attribute__((ext_vector_type(8))) short s16x8;
typedef __attribute__((ext_vector_type(4))) float f32x4;

#define B_ 8
#define N_ 2048
#define D_ 128

__device__ __forceinline__ u16 f2bf(float x) {
  union { float f; unsigned u; } v; v.f = x;
  unsigned r = v.u + 0x7FFFu + ((v.u >> 16) & 1u);
  return (u16)(r >> 16);
}

__device__ __forceinline__ s16x8 pack8(f32x4 a, f32x4 b) {
  s16x8 r;
  r[0] = (short)f2bf(a.x); r[1] = (short)f2bf(a.y);
  r[2] = (short)f2bf(a.z); r[3] = (short)f2bf(a.w);
  r[4] = (short)f2bf(b.x); r[5] = (short)f2bf(b.y);
  r[6] = (short)f2bf(b.z); r[7] = (short)f2bf(b.w);
  return r;
}

// D = A(16x32 bf16) * B(32x16 bf16) + C, fp32 accum.
// A: row = lane&15, k = (lane>>4)*8 + i ; B: col = lane&15, k = (lane>>4)*8 + i
// C/D: col = lane&15, row = (lane>>4)*4 + reg   [m89-verified]
__device__ __forceinline__ void mfma16(f32x4& c, s16x8 a, s16x8 b) {
  c = __builtin_amdgcn_mfma_f32_16x16x32_bf16(a, b, c, 0, 0, 0);
}

// ---------------- QKV projection: q,k row-major bf16 [B*N,128]; v transposed [B,128,N] ----------------
__global__ __launch_bounds__(256) void qkv_proj(
    const float* __restrict__ h,
    const float* __restrict__ Wq, const float* __restrict__ bq,
    const float* __restrict__ Wk, const float* __restrict__ bk,
    const float* __restrict__ Wv, const float* __restrict__ bv,
    u16* __restrict__ qg, u16* __restrict__ kg, u16* __restrict__ vTg)
{
  __shared__ u16 hs[64][136];   // h tile, bf16, padded
  __shared__ u16 vTs[128][72];  // v^T tile for coalesced transposed store
  const int t = threadIdx.x;
  const int rowbase = blockIdx.x * 64;

  { // stage h tile -> bf16 LDS
    const int r = t >> 2, cc = (t & 3) * 32;
    const f32x4* src = (const f32x4*)(h + (size_t)(rowbase + r) * D_ + cc);
    #pragma unroll
    for (int j = 0; j < 4; ++j) {
      f32x4 a = src[2 * j], b2 = src[2 * j + 1];
      *(s16x8*)&hs[r][cc + j * 8] = pack8(a, b2);
    }
  }
  __syncthreads();

  const int lane = t & 63, w = t >> 6;
  const int cp = lane & 15, g = lane >> 4;

  for (int it = 0; it < 24; ++it) {
    int idx = w * 24 + it;              // 96 tiles: o(3) x rt(4) x ct(8)
    int o = idx >> 5, rt = (idx >> 3) & 3, ct = idx & 7;
    const float* Wp = (o == 0) ? Wq : (o == 1 ? Wk : Wv);
    const float* bp = (o == 0) ? bq : (o == 1 ? bk : bv);
    f32x4 acc = {0.f, 0.f, 0.f, 0.f};
    const float* wbase = Wp + (size_t)(ct * 16 + cp) * D_ + g * 8;
    #pragma unroll
    for (int kk = 0; kk < 4; ++kk) {
      s16x8 a = *(const s16x8*)&hs[rt * 16 + cp][kk * 32 + g * 8];
      f32x4 w0 = *(const f32x4*)(wbase + kk * 32);
      f32x4 w1 = *(const f32x4*)(wbase + kk * 32 + 4);
      mfma16(acc, a, pack8(w0, w1));
    }
    float bias = bp[ct * 16 + cp];
    if (o < 2) {
      u16* dst = (o == 0 ? qg : kg);
      #pragma unroll
      for (int r = 0; r < 4; ++r) {
        float vv = fmaxf(acc[r] + bias, 0.f);
        dst[(size_t)(rowbase + rt * 16 + g * 4 + r) * D_ + ct * 16 + cp] = f2bf(vv);
      }
    } else {
      #pragma unroll
      for (int r = 0; r < 4; ++r) {
        float vv = fmaxf(acc[r] + bias, 0.f);
        vTs[ct * 16 + cp][rt * 16 + g * 4 + r] = f2bf(vv);
      }
    }
  }
  __syncthreads();
  { // coalesced store of v^T tile
    const int hr = t >> 1, cc = (t & 1) * 32;
    const int bb = rowbase >> 11, ibase = rowbase & 2047;
    u16* dst = vTg + ((size_t)bb * D_ + hr) * N_ + ibase + cc;
    #pragma unroll
    for (int j = 0; j < 4; ++j)
      *(u16x8*)(dst + j * 8) = *(const u16x8*)&vTs[hr][cc + j * 8];
  }
}

// ---------------- Fused flash attention + output projection ----------------
__global__ __launch_bounds__(256) void attn_fused(
    const float* __restrict__ dmask,
    const u16* __restrict__ qg, const u16* __restrict__ kg, const u16* __restrict__ vTg,
    const float* __restrict__ Wo, const float* __restrict__ bo,
    float* __restrict__ outp)
{
  __shared__ u16 Ks[64][136];    // K tile  [j][h], padded (+8)
  __shared__ u16 Vs[128][72];    // V^T tile [h][j], padded (+8)
  __shared__ u16 Ps[4][16][72];  // per-wave P tile [i][j]
  const int t = threadIdx.x;
  const int lane = t & 63, w = t >> 6;
  const int cp = lane & 15, g = lane >> 4;
  const int b = blockIdx.x >> 5;
  const int qbase = (blockIdx.x & 31) << 6;

  // Q fragments held in registers for the whole kernel
  s16x8 qf[4];
  {
    const u16* qrow = qg + (size_t)(b * N_ + qbase + w * 16 + cp) * D_ + g * 8;
    #pragma unroll
    for (int kk = 0; kk < 4; ++kk) qf[kk] = *(const s16x8*)(qrow + kk * 32);
  }

  f32x4 zero = {0.f, 0.f, 0.f, 0.f};
  f32x4 acc[8];
  #pragma unroll
  for (int i = 0; i < 8; ++i) acc[i] = zero;
  float m2[4] = {0.f, 0.f, 0.f, 0.f};   // scores >= 0, so 0 is a safe init
  float l[4] = {0.f, 0.f, 0.f, 0.f};
  const float L2E = 1.44269504f;

  const int krow = t >> 2, kcc = (t & 3) * 32;
  const u16* ksrc0 = kg + (size_t)(b * N_) * D_;
  const int vrow = t >> 1, vcc = (t & 1) * 32;
  const u16* vsrc0 = vTg + (size_t)(b * D_ + vrow) * N_ + vcc;
  const float* dbase0 = dmask + (size_t)(b * N_ + qbase + w * 16 + g * 4) * N_ + cp;

  for (int jt = 0; jt < 32; ++jt) {
    const int jb = jt * 64;
    __syncthreads();  // previous tile fully consumed
    { // stage K tile
      const u16* src = ksrc0 + (size_t)(jb + krow) * D_ + kcc;
      u16x8 v0 = *(const u16x8*)(src);
      u16x8 v1 = *(const u16x8*)(src + 8);
      u16x8 v2 = *(const u16x8*)(src + 16);
      u16x8 v3 = *(const u16x8*)(src + 24);
      *(u16x8*)&Ks[krow][kcc] = v0;
      *(u16x8*)&Ks[krow][kcc + 8] = v1;
      *(u16x8*)&Ks[krow][kcc + 16] = v2;
      *(u16x8*)&Ks[krow][kcc + 24] = v3;
    }
    { // stage V^T tile
      const u16* src = vsrc0 + jb;
      u16x8 v0 = *(const u16x8*)(src);
      u16x8 v1 = *(const u16x8*)(src + 8);
      u16x8 v2 = *(const u16x8*)(src + 16);
      u16x8 v3 = *(const u16x8*)(src + 24);
      *(u16x8*)&Vs[vrow][vcc] = v0;
      *(u16x8*)&Vs[vrow][vcc + 8] = v1;
      *(u16x8*)&Vs[vrow][vcc + 16] = v2;
      *(u16x8*)&Vs[vrow][vcc + 24] = v3;
    }
    // d loads: global -> regs (streamed, no reuse); latency hides under QK MFMAs
    float dl[4][4];
    {
      const float* dp = dbase0 + jb;
      #pragma unroll
      for (int r = 0; r < 4; ++r)
        #pragma unroll
        for (int cn = 0; cn < 4; ++cn)
          dl[cn][r] = dp[(size_t)r * N_ + cn * 16];
    }
    __syncthreads();  // staged data visible

    // S = Q K^T  (per wave: 16 rows x 64 cols)
    f32x4 s[4];
    #pragma unroll
    for (int cn = 0; cn < 4; ++cn) {
      f32x4 sc = zero;
      #pragma unroll
      for (int kk = 0; kk < 4; ++kk) {
        s16x8 kb = *(const s16x8*)&Ks[cn * 16 + cp][kk * 32 + g * 8];
        mfma16(sc, qf[kk], kb);
      }
      s[cn] = sc;
    }

    // scale by d, online softmax (exp2 space)
    float p[4][4], scl[4];
    #pragma unroll
    for (int r = 0; r < 4; ++r) {
      float s2r[4];
      #pragma unroll
      for (int cn = 0; cn < 4; ++cn) s2r[cn] = s[cn][r] * (dl[cn][r] * L2E);
      float pm = fmaxf(fmaxf(s2r[0], s2r[1]), fmaxf(s2r[2], s2r[3]));
      pm = fmaxf(pm, __shfl_xor(pm, 1));
      pm = fmaxf(pm, __shfl_xor(pm, 2));
      pm = fmaxf(pm, __shfl_xor(pm, 4));
      pm = fmaxf(pm, __shfl_xor(pm, 8));
      float mn = fmaxf(m2[r], pm);
      scl[r] = exp2f(m2[r] - mn);
      m2[r] = mn;
      float su = 0.f;
      #pragma unroll
      for (int cn = 0; cn < 4; ++cn) { float pv = exp2f(s2r[cn] - mn); p[cn][r] = pv; su += pv; }
      su += __shfl_xor(su, 1);
      su += __shfl_xor(su, 2);
      su += __shfl_xor(su, 4);
      su += __shfl_xor(su, 8);
      l[r] = l[r] * scl[r] + su;
    }
    #pragma unroll
    for (int ht = 0; ht < 8; ++ht)
      #pragma unroll
      for (int r = 0; r < 4; ++r) acc[ht][r] *= scl[r];

    // P -> per-wave LDS (C-frag layout -> A-frag layout)
    #pragma unroll
    for (int cn = 0; cn < 4; ++cn)
      #pragma unroll
      for (int r = 0; r < 4; ++r)
        Ps[w][g * 4 + r][cn * 16 + cp] = f2bf(p[cn][r]);
    s16x8 pa0 = *(const s16x8*)&Ps[w][cp][g * 8];
    s16x8 pa1 = *(const s16x8*)&Ps[w][cp][32 + g * 8];

    // O += P V
    #pragma unroll
    for (int ht = 0; ht < 8; ++ht) {
      s16x8 b0 = *(const s16x8*)&Vs[ht * 16 + cp][g * 8];
      s16x8 b1 = *(const s16x8*)&Vs[ht * 16 + cp][32 + g * 8];
      mfma16(acc[ht], pa0, b0);
      mfma16(acc[ht], pa1, b1);
    }
  }

  // epilogue: normalize, fuse output projection (res = relu(out @ Wo^T + bo))
  float inv[4];
  #pragma unroll
  for (int r = 0; r < 4; ++r) inv[r] = 1.f / l[r];

  __syncthreads();  // everyone done with Ks/Vs; reuse Ks as out-tile
  #pragma unroll
  for (int ht = 0; ht < 8; ++ht)
    #pragma unroll
    for (int r = 0; r < 4; ++r)
      Ks[w * 16 + g * 4 + r][ht * 16 + cp] = f2bf(acc[ht][r] * inv[r]);

  s16x8 oa[4];
  #pragma unroll
  for (int kk = 0; kk < 4; ++kk)
    oa[kk] = *(const s16x8*)&Ks[w * 16 + cp][kk * 32 + g * 8];

  #pragma unroll
  for (int mt = 0; mt < 8; ++mt) {
    f32x4 rc = zero;
    const float* wsrc = Wo + (size_t)(mt * 16 + cp) * D_ + g * 8;
    #pragma unroll
    for (int kk = 0; kk < 4; ++kk) {
      f32x4 w0 = *(const f32x4*)(wsrc + kk * 32);
      f32x4 w1 = *(const f32x4*)(wsrc + kk * 32 + 4);
      mfma16(rc, oa[kk], pack8(w0, w1));
    }
    float bias = bo[mt * 16 + cp];
    float* obase = outp + (size_t)(b * N_ + qbase + w * 16 + g * 4) * D_ + mt * 16 + cp;
    #pragma unroll
    for (int r = 0; r < 4; ++r)
      obase[(size_t)r * D_] = fmaxf(rc[r] + bias, 0.f);
  }
}

extern "C" void kernel_launch(void* const* d_in, const int* in_sizes, int n_in,
                              void* d_out, int out_size, void* d_ws, size_t ws_size,
                              hipStream_t stream) {
  const float* d  = (const float*)d_in[0];
  const float* h  = (const float*)d_in[1];
  const float* Wv = (const float*)d_in[2];
  const float* bv = (const float*)d_in[3];
  const float* Wk = (const float*)d_in[4];
  const float* bk = (const float*)d_in[5];
  const float* Wq = (const float*)d_in[6];
  const float* bq = (const float*)d_in[7];
  const float* Wo = (const float*)d_in[8];
  const float* bo = (const float*)d_in[9];
  float* outp = (float*)d_out;

  u16* qg  = (u16*)d_ws;                       // [B*N,128] bf16
  u16* kg  = qg + (size_t)B_ * N_ * D_;        // [B*N,128] bf16
  u16* vTg = kg + (size_t)B_ * N_ * D_;        // [B,128,N] bf16

  hipLaunchKernelGGL(qkv_proj, dim3(256), dim3(256), 0, stream,
                     h, Wq, bq, Wk, bk, Wv, bv, qg, kg, vTg);
  hipLaunchKernelGGL(attn_fused, dim3(256), dim3(256), 0, stream,
                     d, qg, kg, vTg, Wo, bo, outp);
}